// Round 1
// baseline (201.842 us; speedup 1.0000x reference)
//
#include <hip/hip_runtime.h>
#include <math.h>

namespace {
constexpr int T_ = 64;
constexpr int D_ = 32;
constexpr int H_ = 4;

// ---------------------------------------------------------------------------
// Prep: gis[q][k] = gi(q,k)/sqrt(8);  bg[h][q][k] = rel_pos_bias[h][q][k]*gi
// gi depends only on log_gi -> compute once, L2-resident for all 8000 blocks.
// ---------------------------------------------------------------------------
__global__ void gi_prep(const float* __restrict__ rel,
                        const float* __restrict__ log_gi,
                        float* __restrict__ gis,
                        float* __restrict__ bg)
{
    const float g = __expf(log_gi[0]);
    const float inv_scale = 0.35355339059327373f; // 1/sqrt(8)
    int tid = blockIdx.x * blockDim.x + threadIdx.x;
    if (tid >= T_ * T_) return;
    int q = tid >> 6, k = tid & 63;
    float lag = (float)(q - k);
    float gi = 0.0f;
    if (k <= q) {  // causal tril; masked entries are *zero*, not -inf
        float z = (lag - g) / (0.5f * g);
        float w = __expf(-0.5f * z * z);
        float r = __expf(-0.1f * fabsf(lag));
        gi = 0.7f * w + 0.3f * r;
    }
    gis[tid] = gi * inv_scale;
#pragma unroll
    for (int h = 0; h < H_; ++h)
        bg[h * (T_ * T_) + tid] = rel[h * (T_ * T_) + tid] * gi;
}

// ---------------------------------------------------------------------------
// Main: one block per (b,n) sequence. 256 threads = 4 waves; wave h = head h,
// lane = query row. fp32 VALU throughout (no fp32 MFMA on CDNA4).
// ---------------------------------------------------------------------------
__global__ __launch_bounds__(256, 2) void gia_main(
    const float* __restrict__ x,
    const float* __restrict__ qw, const float* __restrict__ qb,
    const float* __restrict__ kw, const float* __restrict__ kb,
    const float* __restrict__ vw, const float* __restrict__ vb,
    const float* __restrict__ ow, const float* __restrict__ ob,
    const float* __restrict__ gis, const float* __restrict__ bg,
    float* __restrict__ out)
{
    // xs: x tile, padded +1 (2-way-free banks); reused later as attn output.
    __shared__ __align__(16) float xs[T_][D_ + 1];
    __shared__ __align__(16) float wS[4][D_][D_];   // q,k,v,o weights
    __shared__ float bS[4][D_];
    __shared__ float qT[D_][T_ + 2];                // q transposed, stride 66
    __shared__ __align__(16) float kl[H_][T_][8];   // k rows per head
    __shared__ __align__(16) float vl[H_][T_][8];   // v rows per head

    const int tid = threadIdx.x;
    const int bn  = blockIdx.x;
    const float* xb = x + (size_t)bn * (T_ * D_);

    // ---- stage x tile (coalesced float4) ----
    {
        const float4* xv = (const float4*)xb;
        float4 a = xv[2 * tid], b = xv[2 * tid + 1];
        int t = tid >> 2, c = (tid & 3) * 8;
        xs[t][c + 0] = a.x; xs[t][c + 1] = a.y; xs[t][c + 2] = a.z; xs[t][c + 3] = a.w;
        xs[t][c + 4] = b.x; xs[t][c + 5] = b.y; xs[t][c + 6] = b.z; xs[t][c + 7] = b.w;
    }
    // ---- stage weights + biases (each matrix = 256 float4) ----
    {
        ((float4*)wS[0])[tid] = ((const float4*)qw)[tid];
        ((float4*)wS[1])[tid] = ((const float4*)kw)[tid];
        ((float4*)wS[2])[tid] = ((const float4*)vw)[tid];
        ((float4*)wS[3])[tid] = ((const float4*)ow)[tid];
        if (tid < D_) {
            bS[0][tid] = qb[tid]; bS[1][tid] = kb[tid];
            bS[2][tid] = vb[tid]; bS[3][tid] = ob[tid];
        }
    }
    __syncthreads();

    // ---- QKV projection: thread -> row t = tid/4, cols c0..c0+7 ----
    const int t  = tid >> 2;
    const int g  = tid & 3;
    const int c0 = g * 8;
    {
        float aq[8], ak[8], av[8];
#pragma unroll
        for (int u = 0; u < 8; ++u) {
            aq[u] = bS[0][c0 + u]; ak[u] = bS[1][c0 + u]; av[u] = bS[2][c0 + u];
        }
#pragma unroll 8
        for (int j = 0; j < D_; ++j) {
            float xv = xs[t][j];
#pragma unroll
            for (int u = 0; u < 8; ++u) {
                aq[u] = fmaf(xv, wS[0][j][c0 + u], aq[u]);
                ak[u] = fmaf(xv, wS[1][j][c0 + u], ak[u]);
                av[u] = fmaf(xv, wS[2][j][c0 + u], av[u]);
            }
        }
#pragma unroll
        for (int u = 0; u < 8; ++u) qT[c0 + u][t] = aq[u];
        // head g, dims 0..7: contiguous 16B-aligned
        ((float4*)&kl[g][t][0])[0] = make_float4(ak[0], ak[1], ak[2], ak[3]);
        ((float4*)&kl[g][t][0])[1] = make_float4(ak[4], ak[5], ak[6], ak[7]);
        ((float4*)&vl[g][t][0])[0] = make_float4(av[0], av[1], av[2], av[3]);
        ((float4*)&vl[g][t][0])[1] = make_float4(av[4], av[5], av[6], av[7]);
    }
    __syncthreads();

    // ---- attention: wave h, lane = query row qi ----
    const int h  = tid >> 6;
    const int qi = tid & 63;
    float qr[8];
#pragma unroll
    for (int d = 0; d < 8; ++d) qr[d] = qT[h * 8 + d][qi];

    const float4* bg4p  = (const float4*)(bg  + ((size_t)(h * T_ + qi)) * T_);
    const float4* gis4p = (const float4*)(gis + (size_t)qi * T_);

    float p[T_];                 // full logit row in registers (all static idx)
    float m = -3.0e38f;
#pragma unroll
    for (int k4 = 0; k4 < T_ / 4; ++k4) {
        float4 gi4 = gis4p[k4];
        float4 bb4 = bg4p[k4];
        float gv[4] = {gi4.x, gi4.y, gi4.z, gi4.w};
        float bv[4] = {bb4.x, bb4.y, bb4.z, bb4.w};
#pragma unroll
        for (int j = 0; j < 4; ++j) {
            int kk = k4 * 4 + j;
            float4 k0 = ((const float4*)&kl[h][kk][0])[0]; // broadcast read
            float4 k1 = ((const float4*)&kl[h][kk][0])[1];
            float s;
            s = qr[0] * k0.x;
            s = fmaf(qr[1], k0.y, s);
            s = fmaf(qr[2], k0.z, s);
            s = fmaf(qr[3], k0.w, s);
            s = fmaf(qr[4], k1.x, s);
            s = fmaf(qr[5], k1.y, s);
            s = fmaf(qr[6], k1.z, s);
            s = fmaf(qr[7], k1.w, s);
            float val = fmaf(s, gv[j], bv[j]); // (qk/scale + bias) * gi
            p[kk] = val;
            m = fmaxf(m, val);
        }
    }
    // softmax over all 64 keys (masked entries participate with value 0)
    float sum = 0.0f;
#pragma unroll
    for (int kk = 0; kk < T_; ++kk) {
        float e = __expf(p[kk] - m);
        p[kk] = e;
        sum += e;
    }
    float acc[8];
#pragma unroll
    for (int u = 0; u < 8; ++u) acc[u] = 0.0f;
#pragma unroll
    for (int kk = 0; kk < T_; ++kk) {
        float4 v0 = ((const float4*)&vl[h][kk][0])[0]; // broadcast read
        float4 v1 = ((const float4*)&vl[h][kk][0])[1];
        float pv = p[kk];
        acc[0] = fmaf(pv, v0.x, acc[0]);
        acc[1] = fmaf(pv, v0.y, acc[1]);
        acc[2] = fmaf(pv, v0.z, acc[2]);
        acc[3] = fmaf(pv, v0.w, acc[3]);
        acc[4] = fmaf(pv, v1.x, acc[4]);
        acc[5] = fmaf(pv, v1.y, acc[5]);
        acc[6] = fmaf(pv, v1.z, acc[6]);
        acc[7] = fmaf(pv, v1.w, acc[7]);
    }
    float inv = 1.0f / sum;
    // write attention output into xs (safe: xs reads all completed before
    // the previous __syncthreads; nobody reads xs until the next one)
#pragma unroll
    for (int u = 0; u < 8; ++u) xs[qi][h * 8 + u] = acc[u] * inv;
    __syncthreads();

    // ---- output projection + coalesced store ----
    {
        float ao[8];
#pragma unroll
        for (int u = 0; u < 8; ++u) ao[u] = bS[3][c0 + u];
#pragma unroll 8
        for (int j = 0; j < D_; ++j) {
            float av2 = xs[t][j];
#pragma unroll
            for (int u = 0; u < 8; ++u)
                ao[u] = fmaf(av2, wS[3][j][c0 + u], ao[u]);
        }
        float* op = out + (size_t)bn * (T_ * D_) + t * D_ + c0;
        ((float4*)op)[0] = make_float4(ao[0], ao[1], ao[2], ao[3]);
        ((float4*)op)[1] = make_float4(ao[4], ao[5], ao[6], ao[7]);
    }
}

} // namespace

extern "C" void kernel_launch(void* const* d_in, const int* in_sizes, int n_in,
                              void* d_out, int out_size, void* d_ws, size_t ws_size,
                              hipStream_t stream)
{
    const float* x   = (const float*)d_in[0];
    const float* qw  = (const float*)d_in[1];
    const float* qb  = (const float*)d_in[2];
    const float* kw  = (const float*)d_in[3];
    const float* kb  = (const float*)d_in[4];
    const float* vw  = (const float*)d_in[5];
    const float* vb  = (const float*)d_in[6];
    const float* ow  = (const float*)d_in[7];
    const float* ob  = (const float*)d_in[8];
    const float* rel = (const float*)d_in[9];
    const float* lgi = (const float*)d_in[10];
    float* outp = (float*)d_out;

    float* gis = (float*)d_ws;            // 64*64 floats
    float* bg  = gis + T_ * T_;           // 4*64*64 floats (80 KB total)

    const int bn_count = in_sizes[0] / (T_ * D_);   // 8000

    gi_prep<<<dim3((T_ * T_ + 255) / 256), dim3(256), 0, stream>>>(rel, lgi, gis, bg);
    gia_main<<<dim3(bn_count), dim3(256), 0, stream>>>(
        x, qw, qb, kw, kb, vw, vb, ow, ob, gis, bg, outp);
}

// Round 2
// 76.412 us; speedup vs baseline: 2.6415x; 2.6415x over previous
//
#include <hip/hip_runtime.h>
#include <math.h>

namespace {
constexpr int T_ = 64;
constexpr int D_ = 32;

typedef _Float16 half4 __attribute__((ext_vector_type(4)));
typedef _Float16 half8 __attribute__((ext_vector_type(8)));
typedef float f32x4 __attribute__((ext_vector_type(4)));

// ---------------------------------------------------------------------------
// Prep: build (a) mask tables in per-lane fragment order, fp16, pre-scaled by
// log2(e): tbl[h][nt][mt][lane][8] = {gis[0..3], bg[0..3]} for
// q=(lane&15)+16nt, k=16mt+4*(lane>>4)+r.  (b) fp16 transposed+padded weight
// images wimg[m][col][40] = W_m[k][col].
// ---------------------------------------------------------------------------
__global__ __launch_bounds__(256) void gia_prep(
    const float* __restrict__ qw, const float* __restrict__ kw,
    const float* __restrict__ vw, const float* __restrict__ ow,
    const float* __restrict__ rel, const float* __restrict__ lgi,
    _Float16* __restrict__ tbl, _Float16* __restrict__ wimg)
{
    int t = blockIdx.x * 256 + threadIdx.x;
    if (t < 4096) {
        const float gv = __expf(lgi[0]);
        const float LOG2E = 1.4426950408889634f;
        const float INVS  = 0.35355339059327373f;   // 1/sqrt(8)
        int h = t >> 10, nt = (t >> 8) & 3, mt = (t >> 6) & 3, lane = t & 63;
        int q  = (lane & 15) + 16 * nt;
        int k0 = 16 * mt + 4 * (lane >> 4);
        _Float16 vals[8];
#pragma unroll
        for (int r = 0; r < 4; ++r) {
            int k = k0 + r;
            float lag = (float)(q - k);
            float gi = 0.0f;
            if (k <= q) {   // causal tril (diag included); masked logits = 0
                float z = (lag - gv) / (0.5f * gv);
                gi = 0.7f * __expf(-0.5f * z * z) + 0.3f * __expf(-0.1f * lag);
            }
            vals[r]     = (_Float16)(gi * INVS * LOG2E);
            vals[4 + r] = (_Float16)(rel[(h * 64 + q) * 64 + k] * gi * LOG2E);
        }
#pragma unroll
        for (int i = 0; i < 8; ++i) tbl[t * 8 + i] = vals[i];
    } else if (t < 6656) {
        int wi = t - 4096;
        const float* wp[4] = {qw, kw, vw, ow};
#pragma unroll
        for (int e = 0; e < 2; ++e) {
            int flat = wi * 2 + e;
            int m = flat / 1280, rem = flat % 1280;
            int c2 = rem / 40, kk = rem % 40;
            float v = (kk < 32) ? wp[m][kk * 32 + c2] : 0.0f;
            wimg[flat] = (_Float16)v;
        }
    }
}

// ---------------------------------------------------------------------------
// Main: one block per (b,n). 4 waves. MFMA 16x16x16 f16 everywhere.
// P1: wave=m-tile QKV proj. P2/P3: wave=head, swapped-QK S^T, lane-local
// softmax, shuffle-free PV. P4: wave=m-tile output proj.
// ---------------------------------------------------------------------------
__global__ __launch_bounds__(256) void gia_main(
    const float* __restrict__ x,
    const float* __restrict__ qb_, const float* __restrict__ kb_,
    const float* __restrict__ vb_, const float* __restrict__ ob_,
    const _Float16* __restrict__ tbl, const _Float16* __restrict__ wimg,
    float* __restrict__ out)
{
    __shared__ __align__(16) _Float16 xs[64][40];     // x tile fp16, pad 40
    __shared__ __align__(16) _Float16 wS[4][32][40];  // W^T images (q,k,v,o)
    __shared__ __align__(16) _Float16 qs[64][36];     // Q [q][ch], pad 36
    __shared__ __align__(16) _Float16 ks_[64][36];    // K [key][ch]
    __shared__ __align__(16) _Float16 vT[32][72];     // V^T [ch][key], pad 72
    __shared__ __align__(16) _Float16 os_[64][40];    // attn out [q][ch]
    __shared__ float bS[4][32];

    const int tid  = threadIdx.x;
    const int lane = tid & 63;
    const int w    = tid >> 6;        // wave id
    const int l4   = lane & 15;
    const int g    = lane >> 4;
    const int bn   = blockIdx.x;

    // ---- P0: stage x (fp32->fp16), weight images, biases ----
    {
        const float4* xv = (const float4*)(x + (size_t)bn * 2048);
        float4 a = xv[2 * tid], b = xv[2 * tid + 1];
        int t = tid >> 2, c = (tid & 3) * 8;
        half8 hx;
        hx[0] = (_Float16)a.x; hx[1] = (_Float16)a.y;
        hx[2] = (_Float16)a.z; hx[3] = (_Float16)a.w;
        hx[4] = (_Float16)b.x; hx[5] = (_Float16)b.y;
        hx[6] = (_Float16)b.z; hx[7] = (_Float16)b.w;
        *(half8*)&xs[t][c] = hx;

        const uint4* wsrc = (const uint4*)wimg;          // 640 uint4 total
        uint4* wdst = (uint4*)&wS[0][0][0];
        wdst[tid]        = wsrc[tid];
        wdst[tid + 256]  = wsrc[tid + 256];
        if (tid < 128) wdst[tid + 512] = wsrc[tid + 512];
        if (tid < 128) {
            int m = tid >> 5, i = tid & 31;
            const float* bp = (m == 0) ? qb_ : (m == 1) ? kb_ : (m == 2) ? vb_ : ob_;
            bS[m][i] = bp[i];
        }
    }
    __syncthreads();

    // ---- P1: QKV projection, wave w = m-tile (rows 16w..16w+15) ----
    {
        half4 xa0 = *(const half4*)&xs[16 * w + l4][4 * g];
        half4 xa1 = *(const half4*)&xs[16 * w + l4][4 * g + 16];
#pragma unroll
        for (int m = 0; m < 3; ++m) {
#pragma unroll
            for (int nt = 0; nt < 2; ++nt) {
                half4 wb0 = *(const half4*)&wS[m][l4 + 16 * nt][4 * g];
                half4 wb1 = *(const half4*)&wS[m][l4 + 16 * nt][4 * g + 16];
                f32x4 acc = {};
                acc = __builtin_amdgcn_mfma_f32_16x16x16f16(xa0, wb0, acc, 0, 0, 0);
                acc = __builtin_amdgcn_mfma_f32_16x16x16f16(xa1, wb1, acc, 0, 0, 0);
                float bb = bS[m][l4 + 16 * nt];
                if (m == 0) {
#pragma unroll
                    for (int r = 0; r < 4; ++r)
                        qs[g * 4 + r + 16 * w][l4 + 16 * nt] = (_Float16)(acc[r] + bb);
                } else if (m == 1) {
#pragma unroll
                    for (int r = 0; r < 4; ++r)
                        ks_[g * 4 + r + 16 * w][l4 + 16 * nt] = (_Float16)(acc[r] + bb);
                } else {
                    half4 pv;
#pragma unroll
                    for (int r = 0; r < 4; ++r) pv[r] = (_Float16)(acc[r] + bb);
                    *(half4*)&vT[l4 + 16 * nt][g * 4 + 16 * w] = pv;   // transposed
                }
            }
        }
    }
    __syncthreads();

    // ---- P2+P3: attention, wave = head h ----
    {
        const int h = w;
        half4 kfr[4], qfr[4], vfr[4];
#pragma unroll
        for (int mt = 0; mt < 4; ++mt) {
            half4 v = {};
            if (g < 2) v = *(const half4*)&ks_[l4 + 16 * mt][8 * h + 4 * g];
            kfr[mt] = v;
        }
#pragma unroll
        for (int nt = 0; nt < 4; ++nt) {
            half4 v = {};
            if (g < 2) v = *(const half4*)&qs[l4 + 16 * nt][8 * h + 4 * g];
            qfr[nt] = v;
        }
#pragma unroll
        for (int ks = 0; ks < 4; ++ks) {
            half4 v = {};
            if (l4 < 8) v = *(const half4*)&vT[8 * h + l4][4 * g + 16 * ks];
            vfr[ks] = v;
        }

        f32x4 oacc[4];
#pragma unroll
        for (int i = 0; i < 4; ++i) oacc[i] = (f32x4){};

        const half8* tbl8 = (const half8*)tbl;
#pragma unroll
        for (int nt = 0; nt < 4; ++nt) {
            half8 tb[4];
#pragma unroll
            for (int mt = 0; mt < 4; ++mt)
                tb[mt] = tbl8[((h * 4 + nt) * 4 + mt) * 64 + lane];
            f32x4 s[4];
#pragma unroll
            for (int mt = 0; mt < 4; ++mt) {
                f32x4 z = {};
                // S^T = K * Q^T : lane holds S^T[key=4g+r+16mt][q=l4+16nt]
                s[mt] = __builtin_amdgcn_mfma_f32_16x16x16f16(kfr[mt], qfr[nt], z, 0, 0, 0);
            }
            float p[16];
#pragma unroll
            for (int mt = 0; mt < 4; ++mt)
#pragma unroll
                for (int r = 0; r < 4; ++r)
                    p[mt * 4 + r] =
                        fmaf(s[mt][r], (float)tb[mt][r], (float)tb[mt][4 + r]);
            float mx = p[0];
#pragma unroll
            for (int i = 1; i < 16; ++i) mx = fmaxf(mx, p[i]);
            mx = fmaxf(mx, __shfl_xor(mx, 16));
            mx = fmaxf(mx, __shfl_xor(mx, 32));
            float sum = 0.0f;
#pragma unroll
            for (int i = 0; i < 16; ++i) {
                float e = exp2f(p[i] - mx);   // logits pre-scaled by log2(e)
                p[i] = e;
                sum += e;
            }
            sum += __shfl_xor(sum, 16);
            sum += __shfl_xor(sum, 32);
            float inv = 1.0f / sum;
            // P's (q,key)->lane layout == A-fragment layout: direct PV MFMA.
#pragma unroll
            for (int ks = 0; ks < 4; ++ks) {
                half4 af;
                af[0] = (_Float16)(p[ks * 4 + 0] * inv);
                af[1] = (_Float16)(p[ks * 4 + 1] * inv);
                af[2] = (_Float16)(p[ks * 4 + 2] * inv);
                af[3] = (_Float16)(p[ks * 4 + 3] * inv);
                oacc[nt] = __builtin_amdgcn_mfma_f32_16x16x16f16(af, vfr[ks], oacc[nt], 0, 0, 0);
            }
        }
        if (l4 < 8) {
#pragma unroll
            for (int nt = 0; nt < 4; ++nt)
#pragma unroll
                for (int r = 0; r < 4; ++r)
                    os_[g * 4 + r + 16 * nt][8 * h + l4] = (_Float16)oacc[nt][r];
        }
    }
    __syncthreads();

    // ---- P4: output projection, wave w = m-tile ----
    {
        half4 oa0 = *(const half4*)&os_[16 * w + l4][4 * g];
        half4 oa1 = *(const half4*)&os_[16 * w + l4][4 * g + 16];
        float* yout = out + (size_t)bn * 2048;
#pragma unroll
        for (int nt = 0; nt < 2; ++nt) {
            half4 wb0 = *(const half4*)&wS[3][l4 + 16 * nt][4 * g];
            half4 wb1 = *(const half4*)&wS[3][l4 + 16 * nt][4 * g + 16];
            f32x4 y = {};
            y = __builtin_amdgcn_mfma_f32_16x16x16f16(oa0, wb0, y, 0, 0, 0);
            y = __builtin_amdgcn_mfma_f32_16x16x16f16(oa1, wb1, y, 0, 0, 0);
            float bb = bS[3][l4 + 16 * nt];
#pragma unroll
            for (int r = 0; r < 4; ++r)
                yout[(g * 4 + r + 16 * w) * 32 + l4 + 16 * nt] = y[r] + bb;
        }
    }
}

} // namespace

extern "C" void kernel_launch(void* const* d_in, const int* in_sizes, int n_in,
                              void* d_out, int out_size, void* d_ws, size_t ws_size,
                              hipStream_t stream)
{
    const float* x   = (const float*)d_in[0];
    const float* qw  = (const float*)d_in[1];
    const float* qb  = (const float*)d_in[2];
    const float* kw  = (const float*)d_in[3];
    const float* kb  = (const float*)d_in[4];
    const float* vw  = (const float*)d_in[5];
    const float* vb  = (const float*)d_in[6];
    const float* ow  = (const float*)d_in[7];
    const float* ob  = (const float*)d_in[8];
    const float* rel = (const float*)d_in[9];
    const float* lgi = (const float*)d_in[10];
    float* outp = (float*)d_out;

    _Float16* tbl  = (_Float16*)d_ws;        // 65536 B: mask tables
    _Float16* wimg = tbl + 32768;            // 10240 B: fp16 weight images

    const int bn_count = in_sizes[0] / (T_ * D_);   // 8000

    gia_prep<<<dim3(26), dim3(256), 0, stream>>>(qw, kw, vw, ow, rel, lgi, tbl, wimg);
    gia_main<<<dim3(bn_count), dim3(256), 0, stream>>>(
        x, qb, kb, vb, ob, tbl, wimg, outp);
}

// Round 5
// 66.145 us; speedup vs baseline: 3.0515x; 1.1552x over previous
//
#include <hip/hip_runtime.h>
#include <math.h>

namespace {
constexpr int T_ = 64;
constexpr int D_ = 32;

typedef _Float16 half2 __attribute__((ext_vector_type(2)));
typedef _Float16 half4 __attribute__((ext_vector_type(4)));
typedef _Float16 half8 __attribute__((ext_vector_type(8)));
typedef float f32x4 __attribute__((ext_vector_type(4)));

union H4 { half4 v4; half2 v2[2]; };

// ---------------------------------------------------------------------------
// Prep (runs once):
//   gis32[nt][mt][lane][4]  fp32 = gi(q,k) * (1/sqrt(8)) * log2(e)   (16 KB)
//   ebg  [h][nt][mt][lane][4] fp16 = exp(rel[h][q][k] * gi(q,k))     (32 KB)
//   wimg [m][out_ch][36]    fp16 = W_m[k][out_ch] (k-padded to 36)   (9 KB)
// Fragment addressing: q = (lane&15) + 16*nt, k = 16*mt + 4*(lane>>4) + r.
// Masked (k>q): gis=0, ebg=exp(0)=1 -> logit 0 -> e=1 (matches ref's mask-
// multiplies-logits semantics).
// ---------------------------------------------------------------------------
__global__ __launch_bounds__(256) void gia_prep(
    const float* __restrict__ qw, const float* __restrict__ kw,
    const float* __restrict__ vw, const float* __restrict__ ow,
    const float* __restrict__ rel, const float* __restrict__ lgi,
    float* __restrict__ gis32, _Float16* __restrict__ ebg,
    _Float16* __restrict__ wimg)
{
    int t = blockIdx.x * 256 + threadIdx.x;
    const float gv = __expf(lgi[0]);
    const float LOG2E = 1.4426950408889634f;
    const float INVS  = 0.35355339059327373f;   // 1/sqrt(8)
    if (t < 1024) {
        int nt = t >> 8, mt = (t >> 6) & 3, lane = t & 63;
        int q  = (lane & 15) + 16 * nt;
        int k0 = 16 * mt + 4 * (lane >> 4);
#pragma unroll
        for (int r = 0; r < 4; ++r) {
            int k = k0 + r;
            float gi = 0.0f;
            if (k <= q) {
                float lag = (float)(q - k);
                float z = (lag - gv) / (0.5f * gv);
                gi = 0.7f * __expf(-0.5f * z * z) + 0.3f * __expf(-0.1f * lag);
            }
            gis32[t * 4 + r] = gi * INVS * LOG2E;
        }
    } else if (t < 5120) {
        int e = t - 1024;
        int h = e >> 10, nt = (e >> 8) & 3, mt = (e >> 6) & 3, lane = e & 63;
        int q  = (lane & 15) + 16 * nt;
        int k0 = 16 * mt + 4 * (lane >> 4);
#pragma unroll
        for (int r = 0; r < 4; ++r) {
            int k = k0 + r;
            float gi = 0.0f;
            if (k <= q) {
                float lag = (float)(q - k);
                float z = (lag - gv) / (0.5f * gv);
                gi = 0.7f * __expf(-0.5f * z * z) + 0.3f * __expf(-0.1f * lag);
            }
            ebg[e * 4 + r] = (_Float16)__expf(rel[(h * 64 + q) * 64 + k] * gi);
        }
    } else if (t < 7424) {
        int wi = t - 5120;
        const float* wp[4] = {qw, kw, vw, ow};
#pragma unroll
        for (int e = 0; e < 2; ++e) {
            int flat = wi * 2 + e;              // [m][out_ch][36]
            int m = flat / 1152, rem = flat % 1152;
            int c2 = rem / 36, kk = rem % 36;
            float v = (kk < 32) ? wp[m][kk * 32 + c2] : 0.0f;
            wimg[flat] = (_Float16)v;
        }
    }
}

// ---------------------------------------------------------------------------
// Main: one block per (b,n). 4 waves, MFMA 16x16x16 f16.
// P1 QKV proj -> P2 fragment loads (g<2 zero-guard: head dim 8 < MFMA K=16!)
// -> P3 swapped-QK attention with no-max-sub softmax, MFMA-ones-column row
// sums, deferred normalization -> P4 output projection (scales by 1/sum).
// ---------------------------------------------------------------------------
__global__ __launch_bounds__(256) void gia_main(
    const float* __restrict__ x,
    const float* __restrict__ qb_, const float* __restrict__ kb_,
    const float* __restrict__ vb_, const float* __restrict__ ob_,
    const float* __restrict__ gis32, const _Float16* __restrict__ ebg,
    const _Float16* __restrict__ wimg,
    float* __restrict__ out)
{
    __shared__ __align__(16) _Float16 xs[64][40];     // x tile; reused as os_
    __shared__ __align__(16) _Float16 wS[4][32][36];  // W images [out][in(36)]
    __shared__ __align__(16) _Float16 qs[64][40];     // Q [q][ch]
    __shared__ __align__(16) _Float16 ks_[64][40];    // K [key][ch]
    __shared__ __align__(16) _Float16 vT[37][72];     // V^T [9h+ch][key]; row 9h+8 = ones
    __shared__ float bS[4][32];
    __shared__ float invS[4][64];                     // row sums per (head, q)

    const int tid  = threadIdx.x;
    const int lane = tid & 63;
    const int w    = tid >> 6;
    const int l4   = lane & 15;
    const int g    = lane >> 4;
    const int bn   = blockIdx.x;

    // ---- P0: stage x, weights, biases; ones row ----
    {
        const float4* xv = (const float4*)(x + (size_t)bn * 2048);
        float4 a = xv[2 * tid], b = xv[2 * tid + 1];
        int t = tid >> 2, c = (tid & 3) * 8;
        half8 hx;
        hx[0] = (_Float16)a.x; hx[1] = (_Float16)a.y;
        hx[2] = (_Float16)a.z; hx[3] = (_Float16)a.w;
        hx[4] = (_Float16)b.x; hx[5] = (_Float16)b.y;
        hx[6] = (_Float16)b.z; hx[7] = (_Float16)b.w;
        *(half8*)&xs[t][c] = hx;

        const uint4* wsrc = (const uint4*)wimg;       // 576 uint4 total
        uint4* wdst = (uint4*)&wS[0][0][0];
        wdst[tid]       = wsrc[tid];
        wdst[tid + 256] = wsrc[tid + 256];
        if (tid < 64) wdst[tid + 512] = wsrc[tid + 512];

        if (tid < 128) {                              // vT ones rows (ch 8)
            int h = tid >> 5, j = tid & 31;
            half2 o2 = {(_Float16)1.0f, (_Float16)1.0f};
            *(half2*)&vT[9 * h + 8][2 * j] = o2;
        }
        if (tid < 128) {
            int m = tid >> 5, i = tid & 31;
            const float* bp = (m == 0) ? qb_ : (m == 1) ? kb_ : (m == 2) ? vb_ : ob_;
            bS[m][i] = bp[i];
        }
    }
    __syncthreads();

    // ---- P1: QKV projection, wave w = token rows 16w..16w+15 ----
    {
        half4 xa0 = *(const half4*)&xs[16 * w + l4][4 * g];
        half4 xa1 = *(const half4*)&xs[16 * w + l4][4 * g + 16];
#pragma unroll
        for (int m = 0; m < 3; ++m) {
#pragma unroll
            for (int nt = 0; nt < 2; ++nt) {
                half4 wb0 = *(const half4*)&wS[m][l4 + 16 * nt][4 * g];
                half4 wb1 = *(const half4*)&wS[m][l4 + 16 * nt][4 * g + 16];
                f32x4 acc = {};
                acc = __builtin_amdgcn_mfma_f32_16x16x16f16(xa0, wb0, acc, 0, 0, 0);
                acc = __builtin_amdgcn_mfma_f32_16x16x16f16(xa1, wb1, acc, 0, 0, 0);
                float bb = bS[m][l4 + 16 * nt];
                if (m == 0) {
#pragma unroll
                    for (int r = 0; r < 4; ++r)
                        qs[g * 4 + r + 16 * w][l4 + 16 * nt] = (_Float16)(acc[r] + bb);
                } else if (m == 1) {
#pragma unroll
                    for (int r = 0; r < 4; ++r)
                        ks_[g * 4 + r + 16 * w][l4 + 16 * nt] = (_Float16)(acc[r] + bb);
                } else {
                    half4 pv;
#pragma unroll
                    for (int r = 0; r < 4; ++r) pv[r] = (_Float16)(acc[r] + bb);
                    int c = l4 + 16 * nt;                       // global channel
                    *(half4*)&vT[9 * (c >> 3) + (c & 7)][g * 4 + 16 * w] = pv;
                }
            }
        }
    }
    __syncthreads();

    // ---- P2+P3: attention, wave = head h ----
    {
        const int h = w;
        // Head dim = 8 but MFMA K = 16: lanes g>=2 (k-index 8..15) MUST
        // supply zeros, else they'd read the next head's channels (R4 bug).
        half4 kfr[4], qfr[4], vfr[4];
#pragma unroll
        for (int mt = 0; mt < 4; ++mt) {
            half4 v = {};
            if (g < 2) v = *(const half4*)&ks_[l4 + 16 * mt][8 * h + 4 * g];
            kfr[mt] = v;
        }
#pragma unroll
        for (int nt = 0; nt < 4; ++nt) {
            half4 v = {};
            if (g < 2) v = *(const half4*)&qs[l4 + 16 * nt][8 * h + 4 * g];
            qfr[nt] = v;
        }
        const int vrow = 9 * h + (l4 < 9 ? l4 : 9);   // l4>8 lanes: cols discarded
#pragma unroll
        for (int ks = 0; ks < 4; ++ks)
            vfr[ks] = *(const half4*)&vT[vrow][4 * g + 16 * ks];

        f32x4 oacc[4];
#pragma unroll
        for (int i = 0; i < 4; ++i) oacc[i] = (f32x4){};

#pragma unroll
        for (int nt = 0; nt < 4; ++nt) {
            f32x4 s[4];
#pragma unroll
            for (int mt = 0; mt < 4; ++mt) {
                f32x4 z = {};
                // S^T: lane holds S^T[key=4g+r+16mt][q=l4+16nt]
                s[mt] = __builtin_amdgcn_mfma_f32_16x16x16f16(kfr[mt], qfr[nt], z, 0, 0, 0);
            }
            half4 af[4];
#pragma unroll
            for (int mt = 0; mt < 4; ++mt) {
                f32x4 g4 = *(const f32x4*)&gis32[((nt * 4 + mt) * 64 + lane) * 4];
                half4 eb = *(const half4*)&ebg[(((h * 4 + nt) * 4 + mt) * 64 + lane) * 4];
                // e = 2^(s*gis) * Ebg   (no max-sub: shift-invariant, bounded)
                float t0 = s[mt][0] * g4[0];
                float t1 = s[mt][1] * g4[1];
                float t2 = s[mt][2] * g4[2];
                float t3 = s[mt][3] * g4[3];
                H4 u;
                u.v2[0] = __builtin_bit_cast(half2, __builtin_amdgcn_cvt_pkrtz(exp2f(t0), exp2f(t1)));
                u.v2[1] = __builtin_bit_cast(half2, __builtin_amdgcn_cvt_pkrtz(exp2f(t2), exp2f(t3)));
                af[mt] = u.v4 * eb;                    // 2x v_pk_mul_f16
            }
            // PV: V has ones-column at ch 8 -> lanes l4==8 accumulate row sums
#pragma unroll
            for (int ks = 0; ks < 4; ++ks)
                oacc[nt] = __builtin_amdgcn_mfma_f32_16x16x16f16(af[ks], vfr[ks], oacc[nt], 0, 0, 0);
        }

        _Float16 (*os_)[40] = xs;   // alias: xs dead since P1 barrier
        if (l4 < 8) {
#pragma unroll
            for (int nt = 0; nt < 4; ++nt)
#pragma unroll
                for (int r = 0; r < 4; ++r)
                    os_[g * 4 + r + 16 * nt][8 * h + l4] = (_Float16)oacc[nt][r];
        } else if (l4 == 8) {
#pragma unroll
            for (int nt = 0; nt < 4; ++nt)
#pragma unroll
                for (int r = 0; r < 4; ++r)
                    invS[h][g * 4 + r + 16 * nt] = oacc[nt][r];
        }
    }
    __syncthreads();

    // ---- P4: output projection with deferred softmax normalization ----
    {
        _Float16 (*os_)[40] = xs;
        half4 oa0 = *(const half4*)&os_[16 * w + l4][4 * g];
        half4 oa1 = *(const half4*)&os_[16 * w + l4][4 * g + 16];
        // oa0 spans ch 4g..4g+3 (head g>>1); oa1 spans ch 16+4g.. (head 2+(g>>1))
        float i0 = 1.0f / invS[g >> 1][16 * w + l4];
        float i1 = 1.0f / invS[2 + (g >> 1)][16 * w + l4];
        _Float16 h0 = (_Float16)i0, h1 = (_Float16)i1;
        oa0 *= (half4){h0, h0, h0, h0};
        oa1 *= (half4){h1, h1, h1, h1};
        float* yout = out + (size_t)bn * 2048;
#pragma unroll
        for (int nt = 0; nt < 2; ++nt) {
            half4 wb0 = *(const half4*)&wS[3][l4 + 16 * nt][4 * g];
            half4 wb1 = *(const half4*)&wS[3][l4 + 16 * nt][4 * g + 16];
            f32x4 y = {};
            y = __builtin_amdgcn_mfma_f32_16x16x16f16(oa0, wb0, y, 0, 0, 0);
            y = __builtin_amdgcn_mfma_f32_16x16x16f16(oa1, wb1, y, 0, 0, 0);
            float bb = bS[3][l4 + 16 * nt];
#pragma unroll
            for (int r = 0; r < 4; ++r)
                yout[(g * 4 + r + 16 * w) * 32 + l4 + 16 * nt] = y[r] + bb;
        }
    }
}

} // namespace

extern "C" void kernel_launch(void* const* d_in, const int* in_sizes, int n_in,
                              void* d_out, int out_size, void* d_ws, size_t ws_size,
                              hipStream_t stream)
{
    const float* x   = (const float*)d_in[0];
    const float* qw  = (const float*)d_in[1];
    const float* qb  = (const float*)d_in[2];
    const float* kw  = (const float*)d_in[3];
    const float* kb  = (const float*)d_in[4];
    const float* vw  = (const float*)d_in[5];
    const float* vb  = (const float*)d_in[6];
    const float* ow  = (const float*)d_in[7];
    const float* ob  = (const float*)d_in[8];
    const float* rel = (const float*)d_in[9];
    const float* lgi = (const float*)d_in[10];
    float* outp = (float*)d_out;

    float*    gis32 = (float*)d_ws;                      // 16384 B
    _Float16* ebg   = (_Float16*)((char*)d_ws + 16384);  // 32768 B
    _Float16* wimg  = (_Float16*)((char*)d_ws + 49152);  //  9216 B

    const int bn_count = in_sizes[0] / (T_ * D_);        // 8000

    gia_prep<<<dim3(29), dim3(256), 0, stream>>>(qw, kw, vw, ow, rel, lgi,
                                                 gis32, ebg, wimg);
    gia_main<<<dim3(bn_count), dim3(256), 0, stream>>>(
        x, qb, kb, vb, ob, gis32, ebg, wimg, outp);
}

// Round 6
// 65.625 us; speedup vs baseline: 3.0757x; 1.0079x over previous
//
#include <hip/hip_runtime.h>
#include <math.h>

namespace {
constexpr int T_ = 64;
constexpr int D_ = 32;

typedef _Float16 half2 __attribute__((ext_vector_type(2)));
typedef _Float16 half4 __attribute__((ext_vector_type(4)));
typedef _Float16 half8 __attribute__((ext_vector_type(8)));
typedef float f32x4 __attribute__((ext_vector_type(4)));

union H4 { half4 v4; half2 v2[2]; };
union H8 { half8 v8; half4 v4[2]; };

// ---------------------------------------------------------------------------
// Prep (runs once):
//   gis32[nt][mt][lane][4] fp32 = gi(q,k)/sqrt(8)*log2e              (16 KB)
//   lb32 [h][nt][mt][lane][4] fp32 = rel[h][q][k]*gi(q,k)*log2e      (64 KB)
//   wimg [m][out_ch][36]   fp16 = W_m[k][out_ch], k-padded to 36     (9 KB)
// Fragment addressing: q = (lane&15) + 16*nt, k = 16*mt + 4*(lane>>4) + r.
// Masked (k>q): gis=0, lb=0 -> logit 0 -> e=1 (matches ref: mask multiplies
// logits by 0, masked keys still participate in softmax).
// ---------------------------------------------------------------------------
__global__ __launch_bounds__(256) void gia_prep(
    const float* __restrict__ qw, const float* __restrict__ kw,
    const float* __restrict__ vw, const float* __restrict__ ow,
    const float* __restrict__ rel, const float* __restrict__ lgi,
    float* __restrict__ gis32, float* __restrict__ lb32,
    _Float16* __restrict__ wimg)
{
    int t = blockIdx.x * 256 + threadIdx.x;
    const float gv = __expf(lgi[0]);
    const float LOG2E = 1.4426950408889634f;
    const float INVS  = 0.35355339059327373f;   // 1/sqrt(8)
    if (t < 1024) {
        int nt = t >> 8, mt = (t >> 6) & 3, lane = t & 63;
        int q  = (lane & 15) + 16 * nt;
        int k0 = 16 * mt + 4 * (lane >> 4);
#pragma unroll
        for (int r = 0; r < 4; ++r) {
            int k = k0 + r;
            float gi = 0.0f;
            if (k <= q) {
                float lag = (float)(q - k);
                float z = (lag - gv) / (0.5f * gv);
                gi = 0.7f * __expf(-0.5f * z * z) + 0.3f * __expf(-0.1f * lag);
            }
            gis32[t * 4 + r] = gi * INVS * LOG2E;
        }
    } else if (t < 5120) {
        int e = t - 1024;
        int h = e >> 10, nt = (e >> 8) & 3, mt = (e >> 6) & 3, lane = e & 63;
        int q  = (lane & 15) + 16 * nt;
        int k0 = 16 * mt + 4 * (lane >> 4);
#pragma unroll
        for (int r = 0; r < 4; ++r) {
            int k = k0 + r;
            float gi = 0.0f;
            if (k <= q) {
                float lag = (float)(q - k);
                float z = (lag - gv) / (0.5f * gv);
                gi = 0.7f * __expf(-0.5f * z * z) + 0.3f * __expf(-0.1f * lag);
            }
            lb32[e * 4 + r] = rel[(h * 64 + q) * 64 + k] * gi * LOG2E;
        }
    } else if (t < 7424) {
        int wi = t - 5120;
        const float* wp[4] = {qw, kw, vw, ow};
#pragma unroll
        for (int e = 0; e < 2; ++e) {
            int flat = wi * 2 + e;              // [m][out_ch][36]
            int m = flat / 1152, rem = flat % 1152;
            int c2 = rem / 36, kk = rem % 36;
            float v = (kk < 32) ? wp[m][kk * 32 + c2] : 0.0f;
            wimg[flat] = (_Float16)v;
        }
    }
}

// ---------------------------------------------------------------------------
// Main: one block per (b,n). 4 waves. LDS 27.0 KB -> 6 blocks/CU.
// P1 QKV proj (16x16x32, one MFMA per output tile) -> P3 swapped-QK
// attention (16x16x16, g<2 zero-guard since HD=8<K=16), fma+exp2 softmax,
// ones-column row sums, deferred normalization -> P4 o-proj (16x16x32,
// weights/bias hoisted from global at entry).
// ---------------------------------------------------------------------------
__global__ __launch_bounds__(256, 6) void gia_main(
    const float* __restrict__ x,
    const float* __restrict__ qb_, const float* __restrict__ kb_,
    const float* __restrict__ vb_, const float* __restrict__ ob_,
    const float* __restrict__ gis32, const float* __restrict__ lb32,
    const _Float16* __restrict__ wimg,
    float* __restrict__ out)
{
    __shared__ __align__(16) _Float16 xs[64][40];     // x tile; reused as os_
    __shared__ __align__(16) _Float16 wS[3][32][36];  // q,k,v W images
    __shared__ __align__(16) _Float16 qs[64][36];     // Q [q][ch]
    __shared__ __align__(16) _Float16 ks_[64][36];    // K [key][ch]
    __shared__ __align__(16) _Float16 vT[36][68];     // V^T [9h+ch][key]; row 9h+8 = ones
    __shared__ float bS[3][32];
    __shared__ _Float16 invS[4][64];                  // row sums (head, q)

    const int tid  = threadIdx.x;
    const int lane = tid & 63;
    const int w    = tid >> 6;
    const int l4   = lane & 15;
    const int g    = lane >> 4;
    const int bn   = blockIdx.x;

    // ---- hoisted P4 operands (global, L1/L2-resident, no deps) ----
    H8 wo[2]; float obv[2];
#pragma unroll
    for (int nt = 0; nt < 2; ++nt) {
        const _Float16* wp = wimg + 3 * 1152 + (l4 + 16 * nt) * 36 + 8 * g;
        wo[nt].v4[0] = *(const half4*)wp;
        wo[nt].v4[1] = *(const half4*)(wp + 4);
        obv[nt] = ob_[l4 + 16 * nt];
    }

    // ---- P0: stage x, q/k/v weights, biases; ones row ----
    {
        const float4* xv = (const float4*)(x + (size_t)bn * 2048);
        float4 a = xv[2 * tid], b = xv[2 * tid + 1];
        int t = tid >> 2, c = (tid & 3) * 8;
        half8 hx;
        hx[0] = (_Float16)a.x; hx[1] = (_Float16)a.y;
        hx[2] = (_Float16)a.z; hx[3] = (_Float16)a.w;
        hx[4] = (_Float16)b.x; hx[5] = (_Float16)b.y;
        hx[6] = (_Float16)b.z; hx[7] = (_Float16)b.w;
        *(half8*)&xs[t][c] = hx;

        const uint4* wsrc = (const uint4*)wimg;       // q,k,v = 432 uint4
        uint4* wdst = (uint4*)&wS[0][0][0];
        wdst[tid] = wsrc[tid];
        if (tid < 176) wdst[tid + 256] = wsrc[tid + 256];

        if (tid < 128) {                              // vT ones rows (ch 8)
            int h = tid >> 5, j = tid & 31;
            half2 o2 = {(_Float16)1.0f, (_Float16)1.0f};
            *(half2*)&vT[9 * h + 8][2 * j] = o2;
        }
        if (tid < 96) {
            int m = tid >> 5, i = tid & 31;
            const float* bp = (m == 0) ? qb_ : (m == 1) ? kb_ : vb_;
            bS[m][i] = bp[i];
        }
    }
    __syncthreads();

    // ---- P1: QKV projection, wave w = token rows 16w..16w+15 ----
    {
        half8 xa = *(const half8*)&xs[16 * w + l4][8 * g];   // A: k = 8g..8g+7
#pragma unroll
        for (int m = 0; m < 3; ++m) {
#pragma unroll
            for (int nt = 0; nt < 2; ++nt) {
                H8 wb;
                wb.v4[0] = *(const half4*)&wS[m][l4 + 16 * nt][8 * g];
                wb.v4[1] = *(const half4*)&wS[m][l4 + 16 * nt][8 * g + 4];
                f32x4 acc = {};
                acc = __builtin_amdgcn_mfma_f32_16x16x32_f16(xa, wb.v8, acc, 0, 0, 0);
                float bb = bS[m][l4 + 16 * nt];
                if (m == 0) {
#pragma unroll
                    for (int r = 0; r < 4; ++r)
                        qs[g * 4 + r + 16 * w][l4 + 16 * nt] = (_Float16)(acc[r] + bb);
                } else if (m == 1) {
#pragma unroll
                    for (int r = 0; r < 4; ++r)
                        ks_[g * 4 + r + 16 * w][l4 + 16 * nt] = (_Float16)(acc[r] + bb);
                } else {
                    half4 pv;
#pragma unroll
                    for (int r = 0; r < 4; ++r) pv[r] = (_Float16)(acc[r] + bb);
                    int c = l4 + 16 * nt;                       // global channel
                    *(half4*)&vT[9 * (c >> 3) + (c & 7)][g * 4 + 16 * w] = pv;
                }
            }
        }
    }
    __syncthreads();

    // ---- P2+P3: attention, wave = head h (16x16x16: HD=8 < K=16 -> g>=2
    // lanes MUST be zero, else they read the next head's channels) ----
    {
        const int h = w;
        half4 kfr[4], qfr[4], vfr[4];
#pragma unroll
        for (int mt = 0; mt < 4; ++mt) {
            half4 v = {};
            if (g < 2) v = *(const half4*)&ks_[l4 + 16 * mt][8 * h + 4 * g];
            kfr[mt] = v;
        }
#pragma unroll
        for (int nt = 0; nt < 4; ++nt) {
            half4 v = {};
            if (g < 2) v = *(const half4*)&qs[l4 + 16 * nt][8 * h + 4 * g];
            qfr[nt] = v;
        }
        const int vrow = 9 * h + (l4 < 9 ? l4 : 8);   // cols l4>8 discarded
#pragma unroll
        for (int ks = 0; ks < 4; ++ks)
            vfr[ks] = *(const half4*)&vT[vrow][4 * g + 16 * ks];

        f32x4 oacc[4];
#pragma unroll
        for (int i = 0; i < 4; ++i) oacc[i] = (f32x4){};

#pragma unroll
        for (int nt = 0; nt < 4; ++nt) {
            f32x4 s[4];
#pragma unroll
            for (int mt = 0; mt < 4; ++mt) {
                f32x4 z = {};
                // S^T: lane holds S^T[key=4g+r+16mt][q=l4+16nt]
                s[mt] = __builtin_amdgcn_mfma_f32_16x16x16f16(kfr[mt], qfr[nt], z, 0, 0, 0);
            }
            half4 af[4];
#pragma unroll
            for (int mt = 0; mt < 4; ++mt) {
                f32x4 g4  = *(const f32x4*)&gis32[((nt * 4 + mt) * 64 + lane) * 4];
                f32x4 lbv = *(const f32x4*)&lb32[(((h * 4 + nt) * 4 + mt) * 64 + lane) * 4];
                // e = 2^(s*gis + lb)   (no max-sub: shift-invariant, bounded)
                float t0 = fmaf(s[mt][0], g4[0], lbv[0]);
                float t1 = fmaf(s[mt][1], g4[1], lbv[1]);
                float t2 = fmaf(s[mt][2], g4[2], lbv[2]);
                float t3 = fmaf(s[mt][3], g4[3], lbv[3]);
                H4 u;
                u.v2[0] = __builtin_bit_cast(half2, __builtin_amdgcn_cvt_pkrtz(exp2f(t0), exp2f(t1)));
                u.v2[1] = __builtin_bit_cast(half2, __builtin_amdgcn_cvt_pkrtz(exp2f(t2), exp2f(t3)));
                af[mt] = u.v4;
            }
            // PV: V ones-column at ch 8 -> lanes l4==8 accumulate row sums
#pragma unroll
            for (int ks = 0; ks < 4; ++ks)
                oacc[nt] = __builtin_amdgcn_mfma_f32_16x16x16f16(af[ks], vfr[ks], oacc[nt], 0, 0, 0);
        }

        _Float16 (*os_)[40] = xs;   // alias: xs dead since P1 barrier
        if (l4 < 8) {
#pragma unroll
            for (int nt = 0; nt < 4; ++nt)
#pragma unroll
                for (int r = 0; r < 4; ++r)
                    os_[g * 4 + r + 16 * nt][8 * h + l4] = (_Float16)oacc[nt][r];
        } else if (l4 == 8) {
#pragma unroll
            for (int nt = 0; nt < 4; ++nt)
#pragma unroll
                for (int r = 0; r < 4; ++r)
                    invS[h][g * 4 + r + 16 * nt] = (_Float16)oacc[nt][r];
        }
    }
    __syncthreads();

    // ---- P4: o-proj (16x16x32) with deferred softmax normalization ----
    {
        _Float16 (*os_)[40] = xs;
        // A-frag k = 8g..8g+7 = exactly head g -> single norm factor per lane
        half4 o0 = *(const half4*)&os_[16 * w + l4][8 * g];
        half4 o1 = *(const half4*)&os_[16 * w + l4][8 * g + 4];
        float iv = 1.0f / (float)invS[g][16 * w + l4];
        _Float16 hv = (_Float16)iv;
        o0 *= (half4){hv, hv, hv, hv};
        o1 *= (half4){hv, hv, hv, hv};
        H8 oa; oa.v4[0] = o0; oa.v4[1] = o1;
        float* yout = out + (size_t)bn * 2048;
#pragma unroll
        for (int nt = 0; nt < 2; ++nt) {
            f32x4 y = {};
            y = __builtin_amdgcn_mfma_f32_16x16x32_f16(oa.v8, wo[nt].v8, y, 0, 0, 0);
#pragma unroll
            for (int r = 0; r < 4; ++r)
                yout[(g * 4 + r + 16 * w) * 32 + l4 + 16 * nt] = y[r] + obv[nt];
        }
    }
}

} // namespace

extern "C" void kernel_launch(void* const* d_in, const int* in_sizes, int n_in,
                              void* d_out, int out_size, void* d_ws, size_t ws_size,
                              hipStream_t stream)
{
    const float* x   = (const float*)d_in[0];
    const float* qw  = (const float*)d_in[1];
    const float* qb  = (const float*)d_in[2];
    const float* kw  = (const float*)d_in[3];
    const float* kb  = (const float*)d_in[4];
    const float* vw  = (const float*)d_in[5];
    const float* vb  = (const float*)d_in[6];
    const float* ow  = (const float*)d_in[7];
    const float* ob  = (const float*)d_in[8];
    const float* rel = (const float*)d_in[9];
    const float* lgi = (const float*)d_in[10];
    float* outp = (float*)d_out;

    float*    gis32 = (float*)d_ws;                      // 16384 B
    float*    lb32  = (float*)((char*)d_ws + 16384);     // 65536 B
    _Float16* wimg  = (_Float16*)((char*)d_ws + 81920);  //  9216 B

    const int bn_count = in_sizes[0] / (T_ * D_);        // 8000

    gia_prep<<<dim3(29), dim3(256), 0, stream>>>(qw, kw, vw, ow, rel, lgi,
                                                 gis32, lb32, wimg);
    gia_main<<<dim3(bn_count), dim3(256), 0, stream>>>(
        x, qb, kb, vb, ob, gis32, lb32, wimg, outp);
}